// Round 6
// baseline (859.920 us; speedup 1.0000x reference)
//
#include <hip/hip_runtime.h>
#include <hip/hip_bf16.h>
#include <math.h>

#define B_ 8
#define N_ 900
#define D_ 256
#define S_ 21760
#define H_ 8
#define DH 32
#define FF_ 2048
#define NROWS (B_*N_)   // 7200

typedef __attribute__((ext_vector_type(8))) short bf16x8;
typedef __attribute__((ext_vector_type(4))) float f32x4;

union BU { bf16x8 v; short s[8]; unsigned long long u[2]; };

static __device__ inline short f2bf_s(float x) {
  __hip_bfloat16 h = __float2bfloat16(x);
  return *reinterpret_cast<short*>(&h);
}

// ---------------------------------------------------------------- RoPE
__global__ __launch_bounds__(128) void rope_kernel(
    const float* __restrict__ tgt, const float* __restrict__ qpos,
    const float* __restrict__ boxes, float* __restrict__ out)
{
  int row = blockIdx.x;
  int tid = threadIdx.x;
  const float* x = tgt  + (size_t)row * D_;
  const float* p = qpos + (size_t)row * D_;
  float a0 = x[2*tid]   + p[2*tid];
  float a1 = x[2*tid+1] + p[2*tid+1];
  float o0 = a0, o1 = a1;
  if (tid < 126) {
    int band = tid / 42;
    int fi   = tid - band * 42;
    float freq = powf(10000.0f, -(float)fi / 42.0f);
    float cx = boxes[(size_t)row*4 + 0];
    float cy = boxes[(size_t)row*4 + 1];
    float v  = (band == 0) ? cx : (band == 1 ? cy : cx * cy);
    if (band == 2) freq *= 0.1f;
    float ang = v * freq;
    float c = cosf(ang), s = sinf(ang);
    o0 = a0 * c - a1 * s;
    o1 = a1 * c + a0 * s;
  }
  out[(size_t)row*D_ + 2*tid]   = o0;
  out[(size_t)row*D_ + 2*tid+1] = o1;
}

// ---------------------------------------------------------------- weight transpose+convert
// Layout (elems): qk 0 (wq@0, wk@65536), wv 131072, sa 196608,
// off 262144, aw 327680, val 360448, co 425984, ff1 491520, ff2 1015808.
__global__ __launch_bounds__(256) void wtrans_kernel(
    const float* __restrict__ wq, const float* __restrict__ wk,
    const float* __restrict__ wv, const float* __restrict__ sa_wo,
    const float* __restrict__ offw, const float* __restrict__ valw,
    const float* __restrict__ cow, const float* __restrict__ aww,
    const float* __restrict__ ff1w, const float* __restrict__ ff2w,
    short* __restrict__ Wt)
{
  int bid = blockIdx.x;
  const float* W; short* out; int K, N, tile;
  if (bid < 448) {
    int wi = bid >> 6; tile = bid & 63; K = 256; N = 256;
    const float* tab[7] = {wq, wk, wv, sa_wo, offw, valw, cow};
    const int   off[7]  = {0, 65536, 131072, 196608, 262144, 360448, 425984};
    W = tab[wi]; out = Wt + off[wi];
  } else if (bid < 480) {
    tile = bid - 448; K = 256; N = 128; W = aww; out = Wt + 327680;
  } else if (bid < 992) {
    tile = bid - 480; K = 256; N = 2048; W = ff1w; out = Wt + 491520;
  } else {
    tile = bid - 992; K = 2048; N = 256; W = ff2w; out = Wt + 1015808;
  }
  int ntn = N >> 5;
  int tk = tile / ntn, tn = tile - tk * ntn;
  __shared__ float t[32][33];
  int c = threadIdx.x & 31, rr = threadIdx.x >> 5;
  #pragma unroll
  for (int i = 0; i < 4; ++i)
    t[rr + i*8][c] = W[(size_t)(tk*32 + rr + i*8) * N + tn*32 + c];
  __syncthreads();
  #pragma unroll
  for (int i = 0; i < 4; ++i)
    out[(size_t)(tn*32 + rr + i*8) * K + tk*32 + c] = f2bf_s(t[c][rr + i*8]);
}

// ---------------------------------------------------------------- MFMA GEMM (round-4 structure)
// C[M,N] = A[M,K] @ W + bias, W as Wt[N][K] bf16 (L2-resident).
// Whole 256-wide K-strip staged in LDS (XOR-swizzled); barrier-light loop.
// OUTMODE: 0 fp32 [M][N]; 1 bf16 [M][N]; 2 bf16 attn-V transpose;
//          3 dual bf16 (n<256 -> Cp, else Cp2); 4 dual fp32 (Cp/Cp2[128]).
template<int BM, int KK, bool ABF16, bool A2ADD, bool RELU, int OUTMODE>
__global__ __launch_bounds__(256) void mgemm_kernel(
    const void* __restrict__ Ap, const float* __restrict__ A2p,
    const short* __restrict__ Wt,
    const float* __restrict__ bias, const float* __restrict__ bias2,
    void* __restrict__ Cp, void* __restrict__ Cp2, int M, int N)
{
  constexpr int MS = BM / 16;
  __shared__ short As[BM * 256];
  int tid = threadIdx.x;
  int w = tid >> 6, lane = tid & 63;
  int g = lane >> 4, r = lane & 15;
  int m0 = blockIdx.x * BM;
  int nw = blockIdx.y * 256 + w * 64;
  bool active = nw < N;

  f32x4 acc[MS][4];
  #pragma unroll
  for (int i = 0; i < MS; ++i)
    #pragma unroll
    for (int j = 0; j < 4; ++j) acc[i][j] = (f32x4){0.f,0.f,0.f,0.f};

  for (int kb = 0; kb < KK; kb += 256) {
    if (KK > 256 && kb) __syncthreads();
    #pragma unroll
    for (int i = 0; i < BM/8; ++i) {
      int u = i*256 + tid;
      int row = u >> 5, c8 = u & 31;
      BU pk;
      if (ABF16) {
        pk.v = *(const bf16x8*)((const short*)Ap + (size_t)(m0+row)*KK + kb + c8*8);
      } else {
        const float* ap = (const float*)Ap + (size_t)(m0+row)*KK + kb + c8*8;
        float4 a0 = *(const float4*)ap;
        float4 a1 = *(const float4*)(ap + 4);
        if (A2ADD) {
          const float* a2 = A2p + (size_t)(m0+row)*KK + kb + c8*8;
          float4 b0 = *(const float4*)a2;
          float4 b1 = *(const float4*)(a2 + 4);
          a0.x += b0.x; a0.y += b0.y; a0.z += b0.z; a0.w += b0.w;
          a1.x += b1.x; a1.y += b1.y; a1.z += b1.z; a1.w += b1.w;
        }
        pk.s[0]=f2bf_s(a0.x); pk.s[1]=f2bf_s(a0.y); pk.s[2]=f2bf_s(a0.z); pk.s[3]=f2bf_s(a0.w);
        pk.s[4]=f2bf_s(a1.x); pk.s[5]=f2bf_s(a1.y); pk.s[6]=f2bf_s(a1.z); pk.s[7]=f2bf_s(a1.w);
      }
      int col = (c8*8) ^ ((row & 7) << 3);
      *(bf16x8*)&As[row*256 + col] = pk.v;
    }
    __syncthreads();
    if (active) {
      #pragma unroll
      for (int kk = 0; kk < 8; ++kk) {
        BU bfr[4];
        #pragma unroll
        for (int ns = 0; ns < 4; ++ns) {
          const short* wp = Wt + (size_t)(nw + ns*16 + r)*KK + kb + kk*32;
          bfr[ns].u[0] = *(const unsigned long long*)(wp + 4*g);
          bfr[ns].u[1] = *(const unsigned long long*)(wp + 16 + 4*g);
        }
        #pragma unroll
        for (int ms = 0; ms < MS; ++ms) {
          int row = ms*16 + r;
          int c0 = (kk*32 + g*4)      ^ ((r & 7) << 3);
          int c1 = (kk*32 + 16 + g*4) ^ ((r & 7) << 3);
          BU af;
          af.u[0] = *(const unsigned long long*)&As[row*256 + c0];
          af.u[1] = *(const unsigned long long*)&As[row*256 + c1];
          #pragma unroll
          for (int ns = 0; ns < 4; ++ns)
            acc[ms][ns] = __builtin_amdgcn_mfma_f32_16x16x32_bf16(
                af.v, bfr[ns].v, acc[ms][ns], 0, 0, 0);
        }
      }
    }
  }
  if (!active) return;

  #pragma unroll
  for (int ms = 0; ms < MS; ++ms) {
    #pragma unroll
    for (int ns = 0; ns < 4; ++ns) {
      int n = nw + ns*16 + r;
      float bs;
      if (OUTMODE == 3 || OUTMODE == 4) bs = (n < 256) ? bias[n] : bias2[n - 256];
      else bs = bias[n];
      #pragma unroll
      for (int j = 0; j < 4; ++j) {
        int m = m0 + ms*16 + g*4 + j;
        float v = acc[ms][ns][j] + bs;
        if (RELU) v = fmaxf(v, 0.f);
        if (OUTMODE == 0) {
          ((float*)Cp)[(size_t)m*N + n] = v;
        } else if (OUTMODE == 1) {
          ((short*)Cp)[(size_t)m*N + n] = f2bf_s(v);
        } else if (OUTMODE == 2) {
          int bb = m / N_, nn = m - bb * N_;
          int hh = n >> 5, dd = n & 31;
          ((short*)Cp)[((size_t)((bb*H_ + hh)*DH + dd))*N_ + nn] = f2bf_s(v);
        } else if (OUTMODE == 3) {
          if (n < 256) ((short*)Cp )[(size_t)m*256 + n]       = f2bf_s(v);
          else         ((short*)Cp2)[(size_t)m*256 + (n-256)] = f2bf_s(v);
        } else {
          if (n < 256) ((float*)Cp )[(size_t)m*256 + n]       = v;
          else         ((float*)Cp2)[(size_t)m*128 + (n-256)] = v;
        }
      }
    }
  }
}

// ---------------------------------------------------------------- value GEMM, streaming
// C[M,256] = A[M,256] @ W + bias, bf16 out. W (256x256 bf16 = 128 KB) lives
// in LDS fragment-major (one ds_read_b128 per B-fragment). 8 waves/block,
// 1 block/CU; each wave grid-strides over 16-row strips with ZERO barriers
// after the W stage; A goes global->reg->cvt->MFMA with 1-deep strip prefetch.
__global__ __launch_bounds__(512) void vstream_kernel(
    const float* __restrict__ Ap, const short* __restrict__ Wt,
    const float* __restrict__ bias, short* __restrict__ Cp, int nstrips)
{
  __shared__ short LW[65536];   // 128 KB
  int tid = threadIdx.x;
  // stage W: 8192 fragments of 16 B, 16 per thread
  #pragma unroll
  for (int i = 0; i < 16; ++i) {
    int f = tid + i*512;
    int fg = f & 3, fr = (f >> 2) & 15, fkk = (f >> 6) & 7, fns = f >> 9;
    const short* wp = Wt + (size_t)(fns*16 + fr)*256 + fkk*32 + 4*fg;
    BU frg;
    frg.u[0] = *(const unsigned long long*)(wp);
    frg.u[1] = *(const unsigned long long*)(wp + 16);
    *(bf16x8*)&LW[f*8] = frg.v;
  }
  __syncthreads();

  int wid = tid >> 6, lane = tid & 63;
  int g = lane >> 4, r = lane & 15;
  int stride = gridDim.x * 8;
  int s = blockIdx.x * 8 + wid;

  float bs[16];
  #pragma unroll
  for (int ns = 0; ns < 16; ++ns) bs[ns] = bias[ns*16 + r];

  float4 pf0[8], pf1[8];
  auto issue = [&](int strip) {
    const float* ap = Ap + (size_t)(strip*16 + r)*256 + 4*g;
    #pragma unroll
    for (int kk = 0; kk < 8; ++kk) {
      pf0[kk] = *(const float4*)(ap + kk*32);
      pf1[kk] = *(const float4*)(ap + kk*32 + 16);
    }
  };

  if (s < nstrips) issue(s);
  for (; s < nstrips; s += stride) {
    bf16x8 af[8];
    #pragma unroll
    for (int kk = 0; kk < 8; ++kk) {
      BU t;
      t.s[0]=f2bf_s(pf0[kk].x); t.s[1]=f2bf_s(pf0[kk].y);
      t.s[2]=f2bf_s(pf0[kk].z); t.s[3]=f2bf_s(pf0[kk].w);
      t.s[4]=f2bf_s(pf1[kk].x); t.s[5]=f2bf_s(pf1[kk].y);
      t.s[6]=f2bf_s(pf1[kk].z); t.s[7]=f2bf_s(pf1[kk].w);
      af[kk] = t.v;
    }
    int sn = s + stride;
    if (sn < nstrips) issue(sn);

    f32x4 acc[16];
    #pragma unroll
    for (int ns = 0; ns < 16; ++ns) acc[ns] = (f32x4){0.f,0.f,0.f,0.f};
    #pragma unroll
    for (int kk = 0; kk < 8; ++kk) {
      #pragma unroll
      for (int ns = 0; ns < 16; ++ns) {
        BU bf;
        bf.v = *(const bf16x8*)&LW[(size_t)((((ns*8 + kk)*16 + r)*4 + g)) * 8];
        acc[ns] = __builtin_amdgcn_mfma_f32_16x16x32_bf16(af[kk], bf.v, acc[ns], 0, 0, 0);
      }
    }
    short* cp = Cp + (size_t)(s*16)*256;
    #pragma unroll
    for (int ns = 0; ns < 16; ++ns) {
      #pragma unroll
      for (int j = 0; j < 4; ++j)
        cp[(size_t)(g*4 + j)*256 + ns*16 + r] = f2bf_s(acc[ns][j] + bs[ns]);
    }
  }
}

// ---------------------------------------------------------------- MFMA flash attention
__global__ __launch_bounds__(64) void mfma_attn_kernel(
    const __hip_bfloat16* __restrict__ Q,
    const __hip_bfloat16* __restrict__ K,
    const __hip_bfloat16* __restrict__ Vt,
    float* __restrict__ O)
{
  const int NQT = 57;
  int wid = blockIdx.x;
  int qt = wid % NQT, bh = wid / NQT;
  int b = bh >> 3, h = bh & 7;
  int lane = threadIdx.x;
  int g = lane >> 4, r = lane & 15;
  int q0 = qt * 16;
  const float scale = 0.17677669529663687f;

  union U { bf16x8 v; short s[8]; unsigned long long u64[2]; };

  U qf;
  {
    int qrow = min(q0 + r, N_ - 1);
    const __hip_bfloat16* qp = Q + ((size_t)(b*N_ + qrow))*D_ + h*DH;
    qf.u64[0] = *(const unsigned long long*)(qp + 4*g);
    qf.u64[1] = *(const unsigned long long*)(qp + 16 + 4*g);
  }

  f32x4 oacc0 = {0.f,0.f,0.f,0.f};
  f32x4 oacc1 = {0.f,0.f,0.f,0.f};
  float m = -1e30f, l = 0.0f;
  const f32x4 zero = {0.f,0.f,0.f,0.f};

  const __hip_bfloat16* vbase0 = Vt + (size_t)(bh*DH + r) * N_;
  const __hip_bfloat16* vbase1 = Vt + (size_t)(bh*DH + 16 + r) * N_;

  for (int kt = 0; kt < N_; kt += 32) {
    U kf0, kf1;
    {
      int kr0 = min(kt + r, N_ - 1);
      int kr1 = min(kt + 16 + r, N_ - 1);
      const __hip_bfloat16* kp0 = K + ((size_t)(b*N_ + kr0))*D_ + h*DH;
      const __hip_bfloat16* kp1 = K + ((size_t)(b*N_ + kr1))*D_ + h*DH;
      kf0.u64[0] = *(const unsigned long long*)(kp0 + 4*g);
      kf0.u64[1] = *(const unsigned long long*)(kp0 + 16 + 4*g);
      kf1.u64[0] = *(const unsigned long long*)(kp1 + 4*g);
      kf1.u64[1] = *(const unsigned long long*)(kp1 + 16 + 4*g);
    }
    f32x4 s0 = __builtin_amdgcn_mfma_f32_16x16x32_bf16(kf0.v, qf.v, zero, 0, 0, 0);
    f32x4 s1 = __builtin_amdgcn_mfma_f32_16x16x32_bf16(kf1.v, qf.v, zero, 0, 0, 0);

    float sc[8];
    #pragma unroll
    for (int j = 0; j < 4; ++j) {
      sc[j]   = (kt + 4*g + j      < N_) ? s0[j] * scale : -1e30f;
      sc[4+j] = (kt + 16 + 4*g + j < N_) ? s1[j] * scale : -1e30f;
    }
    float mx = sc[0];
    #pragma unroll
    for (int j = 1; j < 8; ++j) mx = fmaxf(mx, sc[j]);
    mx = fmaxf(mx, __shfl_xor(mx, 16));
    mx = fmaxf(mx, __shfl_xor(mx, 32));

    float mnew = fmaxf(m, mx);
    float corr = __expf(m - mnew);
    float p[8], ps = 0.f;
    #pragma unroll
    for (int j = 0; j < 8; ++j) { p[j] = __expf(sc[j] - mnew); ps += p[j]; }
    ps += __shfl_xor(ps, 16);
    ps += __shfl_xor(ps, 32);
    l = l * corr + ps;
    m = mnew;
    #pragma unroll
    for (int j = 0; j < 4; ++j) { oacc0[j] *= corr; oacc1[j] *= corr; }

    U pf;
    #pragma unroll
    for (int j = 0; j < 8; ++j) pf.s[j] = f2bf_s(p[j]);

    U vf0, vf1;
    vf0.u64[0] = *(const unsigned long long*)(vbase0 + kt + 4*g);
    vf0.u64[1] = *(const unsigned long long*)(vbase0 + kt + 16 + 4*g);
    vf1.u64[0] = *(const unsigned long long*)(vbase1 + kt + 4*g);
    vf1.u64[1] = *(const unsigned long long*)(vbase1 + kt + 16 + 4*g);

    oacc0 = __builtin_amdgcn_mfma_f32_16x16x32_bf16(vf0.v, pf.v, oacc0, 0, 0, 0);
    oacc1 = __builtin_amdgcn_mfma_f32_16x16x32_bf16(vf1.v, pf.v, oacc1, 0, 0, 0);
  }

  if (q0 + r < N_) {
    float inv = 1.0f / l;
    float* op = O + ((size_t)(b*N_ + q0 + r))*D_ + h*DH;
    #pragma unroll
    for (int j = 0; j < 4; ++j) {
      op[4*g + j]      = oacc0[j] * inv;
      op[16 + 4*g + j] = oacc1[j] * inv;
    }
  }
}

// ---------------------------------------------------------------- add + LayerNorm
__global__ __launch_bounds__(256) void add_ln_kernel(
    const float* __restrict__ X, const float* __restrict__ Y,
    const float* __restrict__ g, const float* __restrict__ beta,
    float* __restrict__ out)
{
  int row = blockIdx.x, tid = threadIdx.x;
  float v = X[(size_t)row*D_ + tid] + Y[(size_t)row*D_ + tid];
  float s = v, s2 = v*v;
  #pragma unroll
  for (int off = 32; off; off >>= 1) {
    s  += __shfl_down(s,  off, 64);
    s2 += __shfl_down(s2, off, 64);
  }
  __shared__ float red[8];
  int wid = tid >> 6, lane = tid & 63;
  if (lane == 0) { red[wid] = s; red[wid+4] = s2; }
  __syncthreads();
  if (tid == 0) {
    float ts  = red[0]+red[1]+red[2]+red[3];
    float ts2 = red[4]+red[5]+red[6]+red[7];
    float mu  = ts * (1.0f/D_);
    float var = ts2 * (1.0f/D_) - mu*mu;
    red[0] = mu;
    red[1] = rsqrtf(fmaxf(var, 0.0f) + 1e-5f);
  }
  __syncthreads();
  float mu = red[0], rr = red[1];
  out[(size_t)row*D_ + tid] = (v - mu)*rr*g[tid] + beta[tid];
}

// ---------------------------------------------------------------- deformable sampling
__global__ __launch_bounds__(256) void sample_kernel(
    const __hip_bfloat16* __restrict__ V, const float* __restrict__ offp,
    const float* __restrict__ awl, const float* __restrict__ refp,
    float* __restrict__ out)
{
  int row = blockIdx.x;
  int b = row / N_;
  int tid = threadIdx.x;
  __shared__ float s_aw[128];
  __shared__ float s_loc[256];
  if (tid < 128) s_aw[tid] = awl[(size_t)row*128 + tid];
  {
    int rem = tid & 31;
    int l = rem >> 3, ax = rem & 1;
    const float norms[4] = {128.f, 64.f, 32.f, 16.f};
    float off = offp[(size_t)row*256 + tid];
    float rp  = refp[((size_t)row*4 + l)*2 + ax];
    s_loc[tid] = rp + off / norms[l];
  }
  __syncthreads();
  if (tid < 8) {
    float mx = -1e30f;
    for (int j = 0; j < 16; ++j) mx = fmaxf(mx, s_aw[tid*16+j]);
    float sum = 0.f;
    for (int j = 0; j < 16; ++j) sum += __expf(s_aw[tid*16+j] - mx);
    float inv = 1.0f / sum;
    for (int j = 0; j < 16; ++j) s_aw[tid*16+j] = __expf(s_aw[tid*16+j] - mx) * inv;
  }
  __syncthreads();
  int h = tid >> 5, d = tid & 31;
  const int dims[4]   = {128, 64, 32, 16};
  const int starts[4] = {0, 16384, 20480, 21504};
  const __hip_bfloat16* Vb = V + ((size_t)b*S_)*D_ + h*DH + d;
  float acc = 0.f;
  #pragma unroll
  for (int l = 0; l < 4; ++l) {
    int Wl = dims[l], st = starts[l];
    #pragma unroll
    for (int p = 0; p < 4; ++p) {
      float lx = s_loc[h*32 + l*8 + p*2 + 0];
      float ly = s_loc[h*32 + l*8 + p*2 + 1];
      float x = lx * Wl - 0.5f, y = ly * Wl - 0.5f;
      float x0f = floorf(x), y0f = floorf(y);
      float fx = x - x0f, fy = y - y0f;
      int x0 = (int)x0f, y0 = (int)y0f;
      float v = 0.f;
      #pragma unroll
      for (int ty = 0; ty < 2; ++ty) {
        int yi = y0 + ty;
        float wy = ty ? fy : (1.f - fy);
        if (yi < 0 || yi >= Wl) continue;
        #pragma unroll
        for (int txi = 0; txi < 2; ++txi) {
          int xi = x0 + txi;
          float wx = txi ? fx : (1.f - fx);
          if (xi < 0 || xi >= Wl) continue;
          v += wy * wx * __bfloat162float(Vb[(size_t)(st + yi*Wl + xi) * D_]);
        }
      }
      acc += s_aw[h*16 + l*4 + p] * v;
    }
  }
  out[(size_t)row*D_ + tid] = acc;
}

// ================================================================ launch
extern "C" void kernel_launch(void* const* d_in, const int* in_sizes, int n_in,
                              void* d_out, int out_size, void* d_ws, size_t ws_size,
                              hipStream_t stream)
{
  const float* tgt    = (const float*)d_in[0];
  const float* memory = (const float*)d_in[1];
  const float* qpos   = (const float*)d_in[2];
  const float* boxes  = (const float*)d_in[3];
  const float* refp   = (const float*)d_in[4];
  const float* wq = (const float*)d_in[5];   const float* bq = (const float*)d_in[6];
  const float* wk = (const float*)d_in[7];   const float* bk = (const float*)d_in[8];
  const float* wv = (const float*)d_in[9];   const float* bv = (const float*)d_in[10];
  const float* sa_wo = (const float*)d_in[11]; const float* sa_bo = (const float*)d_in[12];
  const float* n1g = (const float*)d_in[13]; const float* n1b = (const float*)d_in[14];
  const float* off_w = (const float*)d_in[15]; const float* off_b = (const float*)d_in[16];
  const float* aw_w  = (const float*)d_in[17]; const float* aw_b  = (const float*)d_in[18];
  const float* val_w = (const float*)d_in[19]; const float* val_b = (const float*)d_in[20];
  const float* co_w  = (const float*)d_in[21]; const float* co_b  = (const float*)d_in[22];
  const float* n2g = (const float*)d_in[23]; const float* n2b = (const float*)d_in[24];
  const float* ff1_w = (const float*)d_in[25]; const float* ff1_b = (const float*)d_in[26];
  const float* ff2_w = (const float*)d_in[27]; const float* ff2_b = (const float*)d_in[28];
  const float* n3g = (const float*)d_in[29]; const float* n3b = (const float*)d_in[30];

  char* ws = (char*)d_ws;
  size_t NE = (size_t)NROWS * D_;
  __hip_bfloat16* Vv = (__hip_bfloat16*)ws;     // value bf16 (89 MB)
  __hip_bfloat16* FFM = (__hip_bfloat16*)ws;    // ffn hidden bf16 overlays
  size_t p = (size_t)B_ * S_ * D_ * sizeof(__hip_bfloat16);
  float* A  = (float*)(ws + p); p += NE*4;      // rope out
  float* Qb = (float*)(ws + p); p += NE*4;      // q bf16 / off fp32
  float* Kb = (float*)(ws + p); p += NE*4;      // k bf16 / aw fp32 (first half); Wt in tail
  float* Vh = (float*)(ws + p); p += NE*4;      // Vt bf16 (attn V transposed)
  float* S1 = (float*)(ws + p); p += NE*4;      // attn out / sampled
  float* S2 = (float*)(ws + p); p += NE*4;      // proj out
  float* T1 = (float*)(ws + p); p += NE*4;      // tgt1 / tgt2
  short* Wt = (short*)((char*)Kb + NE*2);       // 3.08 MB in free tail of Kb
  float* out = (float*)d_out;
  (void)ws_size; (void)in_sizes; (void)n_in; (void)out_size;

  const short* qk_t  = Wt;                 // [512][256]
  const short* wv_t  = Wt + 131072;
  const short* sa_t  = Wt + 196608;
  const short* offaw_t = Wt + 262144;      // [384][256]
  const short* val_t = Wt + 360448;
  const short* co_t  = Wt + 425984;
  const short* ff1_t = Wt + 491520;
  const short* ff2_t = Wt + 1015808;

  wtrans_kernel<<<1504, 256, 0, stream>>>(wq, wk, wv, sa_wo, off_w, val_w,
                                          co_w, aw_w, ff1_w, ff2_w, Wt);

  // self-attention branch
  rope_kernel<<<NROWS, 128, 0, stream>>>(tgt, qpos, boxes, A);
  mgemm_kernel<32,256,false,false,false,3><<<dim3(225,2), 256, 0, stream>>>(
      A, nullptr, qk_t, bq, bk, Qb, Kb, NROWS, 512);
  mgemm_kernel<32,256,false,false,false,2><<<dim3(225,1), 256, 0, stream>>>(
      tgt, nullptr, wv_t, bv, nullptr, Vh, nullptr, NROWS, 256);
  mfma_attn_kernel<<<57 * B_ * H_, 64, 0, stream>>>(
      (const __hip_bfloat16*)Qb, (const __hip_bfloat16*)Kb,
      (const __hip_bfloat16*)Vh, S1);
  mgemm_kernel<32,256,false,false,false,0><<<dim3(225,1), 256, 0, stream>>>(
      S1, nullptr, sa_t, sa_bo, nullptr, S2, nullptr, NROWS, 256);
  add_ln_kernel<<<NROWS, 256, 0, stream>>>(tgt, S2, n1g, n1b, T1);

  // cross-attention branch: value GEMM via streaming W-in-LDS kernel
  vstream_kernel<<<256, 512, 0, stream>>>(
      memory, val_t, val_b, (short*)Vv, (B_*S_)/16);
  mgemm_kernel<32,256,false,true,false,4><<<dim3(225,2), 256, 0, stream>>>(
      T1, qpos, offaw_t, off_b, aw_b, Qb, Kb, NROWS, 384);
  sample_kernel<<<NROWS, 256, 0, stream>>>(Vv, Qb, Kb, refp, S1);
  mgemm_kernel<32,256,false,false,false,0><<<dim3(225,1), 256, 0, stream>>>(
      S1, nullptr, co_t, co_b, nullptr, S2, nullptr, NROWS, 256);
  add_ln_kernel<<<NROWS, 256, 0, stream>>>(T1, S2, n2g, n2b, T1);

  // ffn
  mgemm_kernel<32,256,false,false,true,1><<<dim3(225,8), 256, 0, stream>>>(
      T1, nullptr, ff1_t, ff1_b, nullptr, FFM, nullptr, NROWS, FF_);
  mgemm_kernel<32,2048,true,false,false,0><<<dim3(225,1), 256, 0, stream>>>(
      FFM, nullptr, ff2_t, ff2_b, nullptr, S2, nullptr, NROWS, 256);
  add_ln_kernel<<<NROWS, 256, 0, stream>>>(T1, S2, n3g, n3b, out);
}

// Round 7
// 523.259 us; speedup vs baseline: 1.6434x; 1.6434x over previous
//
#include <hip/hip_runtime.h>
#include <hip/hip_bf16.h>
#include <math.h>

#define B_ 8
#define N_ 900
#define D_ 256
#define S_ 21760
#define H_ 8
#define DH 32
#define FF_ 2048
#define NROWS (B_*N_)   // 7200

typedef __attribute__((ext_vector_type(8))) short bf16x8;
typedef __attribute__((ext_vector_type(4))) float f32x4;

union BU { bf16x8 v; short s[8]; unsigned long long u[2]; };

static __device__ inline short f2bf_s(float x) {
  __hip_bfloat16 h = __float2bfloat16(x);
  return *reinterpret_cast<short*>(&h);
}

// ---------------------------------------------------------------- RoPE
__global__ __launch_bounds__(128) void rope_kernel(
    const float* __restrict__ tgt, const float* __restrict__ qpos,
    const float* __restrict__ boxes, float* __restrict__ out)
{
  int row = blockIdx.x;
  int tid = threadIdx.x;
  const float* x = tgt  + (size_t)row * D_;
  const float* p = qpos + (size_t)row * D_;
  float a0 = x[2*tid]   + p[2*tid];
  float a1 = x[2*tid+1] + p[2*tid+1];
  float o0 = a0, o1 = a1;
  if (tid < 126) {
    int band = tid / 42;
    int fi   = tid - band * 42;
    float freq = powf(10000.0f, -(float)fi / 42.0f);
    float cx = boxes[(size_t)row*4 + 0];
    float cy = boxes[(size_t)row*4 + 1];
    float v  = (band == 0) ? cx : (band == 1 ? cy : cx * cy);
    if (band == 2) freq *= 0.1f;
    float ang = v * freq;
    float c = cosf(ang), s = sinf(ang);
    o0 = a0 * c - a1 * s;
    o1 = a1 * c + a0 * s;
  }
  out[(size_t)row*D_ + 2*tid]   = o0;
  out[(size_t)row*D_ + 2*tid+1] = o1;
}

// ---------------------------------------------------------------- weight transpose+convert
// Layout (elems): qk 0 (wq@0, wk@65536), wv 131072, sa 196608,
// off 262144, aw 327680, val 360448, co 425984, ff1 491520, ff2 1015808.
__global__ __launch_bounds__(256) void wtrans_kernel(
    const float* __restrict__ wq, const float* __restrict__ wk,
    const float* __restrict__ wv, const float* __restrict__ sa_wo,
    const float* __restrict__ offw, const float* __restrict__ valw,
    const float* __restrict__ cow, const float* __restrict__ aww,
    const float* __restrict__ ff1w, const float* __restrict__ ff2w,
    short* __restrict__ Wt)
{
  int bid = blockIdx.x;
  const float* W; short* out; int K, N, tile;
  if (bid < 448) {
    int wi = bid >> 6; tile = bid & 63; K = 256; N = 256;
    const float* tab[7] = {wq, wk, wv, sa_wo, offw, valw, cow};
    const int   off[7]  = {0, 65536, 131072, 196608, 262144, 360448, 425984};
    W = tab[wi]; out = Wt + off[wi];
  } else if (bid < 480) {
    tile = bid - 448; K = 256; N = 128; W = aww; out = Wt + 327680;
  } else if (bid < 992) {
    tile = bid - 480; K = 256; N = 2048; W = ff1w; out = Wt + 491520;
  } else {
    tile = bid - 992; K = 2048; N = 256; W = ff2w; out = Wt + 1015808;
  }
  int ntn = N >> 5;
  int tk = tile / ntn, tn = tile - tk * ntn;
  __shared__ float t[32][33];
  int c = threadIdx.x & 31, rr = threadIdx.x >> 5;
  #pragma unroll
  for (int i = 0; i < 4; ++i)
    t[rr + i*8][c] = W[(size_t)(tk*32 + rr + i*8) * N + tn*32 + c];
  __syncthreads();
  #pragma unroll
  for (int i = 0; i < 4; ++i)
    out[(size_t)(tn*32 + rr + i*8) * K + tk*32 + c] = f2bf_s(t[c][rr + i*8]);
}

// ---------------------------------------------------------------- MFMA GEMM, BK=32 dbuf pipeline
// C[M,N] = A[M,K] @ W + bias, W as Wt[N][K] bf16 (L2-resident).
// Double-buffered 32-wide K-chunks; loads for chunk c+1 issued during
// compute(c); ONE barrier per chunk. M % BM == 0 required.
// OUTMODE: 0 fp32 [M][N]; 1 bf16 [M][N]; 2 bf16 attn-V transpose;
//          3 dual bf16 (n<256 -> Cp, else Cp2); 4 dual fp32 (Cp/Cp2[128]).
template<int BM, int KK, bool ABF16, bool A2ADD, bool RELU, int OUTMODE>
__global__ __launch_bounds__(256) void mgemm_kernel(
    const void* __restrict__ Ap, const float* __restrict__ A2p,
    const short* __restrict__ Wt,
    const float* __restrict__ bias, const float* __restrict__ bias2,
    void* __restrict__ Cp, void* __restrict__ Cp2, int M, int N)
{
  constexpr int MS  = BM / 16;
  constexpr int NCH = KK / 32;
  constexpr int NLT = BM * 4;     // loader threads (8 elems each)
  __shared__ short As[2][BM * 32];
  int tid = threadIdx.x;
  int w = tid >> 6, lane = tid & 63;
  int g = lane >> 4, r = lane & 15;
  int m0 = blockIdx.x * BM;
  int nw = blockIdx.y * 256 + w * 64;
  bool active = nw < N;
  bool loader = (NLT >= 256) || (tid < NLT);
  int lrow = (tid % NLT) >> 2;
  int lc8  = (tid & 3) * 8;

  float4 p0, p1, q0, q1;
  bf16x8 pb;

  auto issue = [&](int c) {
    if (!loader || c >= NCH) return;
    size_t base = (size_t)(m0 + lrow) * KK + c*32 + lc8;
    if (ABF16) {
      pb = *(const bf16x8*)((const short*)Ap + base);
    } else {
      p0 = *(const float4*)((const float*)Ap + base);
      p1 = *(const float4*)((const float*)Ap + base + 4);
      if (A2ADD) {
        q0 = *(const float4*)(A2p + base);
        q1 = *(const float4*)(A2p + base + 4);
      }
    }
  };
  auto stage = [&](int c) {
    if (!loader || c >= NCH) return;
    BU pk;
    if (ABF16) {
      pk.v = pb;
    } else {
      float4 a0 = p0, a1 = p1;
      if (A2ADD) {
        a0.x += q0.x; a0.y += q0.y; a0.z += q0.z; a0.w += q0.w;
        a1.x += q1.x; a1.y += q1.y; a1.z += q1.z; a1.w += q1.w;
      }
      pk.s[0]=f2bf_s(a0.x); pk.s[1]=f2bf_s(a0.y); pk.s[2]=f2bf_s(a0.z); pk.s[3]=f2bf_s(a0.w);
      pk.s[4]=f2bf_s(a1.x); pk.s[5]=f2bf_s(a1.y); pk.s[6]=f2bf_s(a1.z); pk.s[7]=f2bf_s(a1.w);
    }
    int col = lc8 ^ ((lrow & 3) << 3);
    *(bf16x8*)&As[c & 1][lrow*32 + col] = pk.v;
  };

  f32x4 acc[MS][4];
  #pragma unroll
  for (int i = 0; i < MS; ++i)
    #pragma unroll
    for (int j = 0; j < 4; ++j) acc[i][j] = (f32x4){0.f,0.f,0.f,0.f};

  issue(0);
  stage(0);
  issue(1);
  __syncthreads();

  for (int c = 0; c < NCH; ++c) {
    if (active) {
      const short* asb = As[c & 1];
      BU bfr[4];
      #pragma unroll
      for (int ns = 0; ns < 4; ++ns) {
        const short* wp = Wt + (size_t)(nw + ns*16 + r) * KK + c*32;
        bfr[ns].u[0] = *(const unsigned long long*)(wp + 4*g);
        bfr[ns].u[1] = *(const unsigned long long*)(wp + 16 + 4*g);
      }
      int swz = (r & 3) << 3;
      #pragma unroll
      for (int ms = 0; ms < MS; ++ms) {
        int row = ms*16 + r;
        BU af;
        af.u[0] = *(const unsigned long long*)&asb[row*32 + ((4*g) ^ swz)];
        af.u[1] = *(const unsigned long long*)&asb[row*32 + ((16 + 4*g) ^ swz)];
        #pragma unroll
        for (int ns = 0; ns < 4; ++ns)
          acc[ms][ns] = __builtin_amdgcn_mfma_f32_16x16x32_bf16(
              af.v, bfr[ns].v, acc[ms][ns], 0, 0, 0);
      }
    }
    stage(c + 1);     // waits the c+1 loads (in flight since last iter), LDS-writes
    issue(c + 2);     // next-next chunk flies under the following compute
    __syncthreads();
  }
  if (!active) return;

  #pragma unroll
  for (int ms = 0; ms < MS; ++ms) {
    #pragma unroll
    for (int ns = 0; ns < 4; ++ns) {
      int n = nw + ns*16 + r;
      float bs;
      if (OUTMODE == 3 || OUTMODE == 4) bs = (n < 256) ? bias[n] : bias2[n - 256];
      else bs = bias[n];
      #pragma unroll
      for (int j = 0; j < 4; ++j) {
        int m = m0 + ms*16 + g*4 + j;
        float v = acc[ms][ns][j] + bs;
        if (RELU) v = fmaxf(v, 0.f);
        if (OUTMODE == 0) {
          ((float*)Cp)[(size_t)m*N + n] = v;
        } else if (OUTMODE == 1) {
          ((short*)Cp)[(size_t)m*N + n] = f2bf_s(v);
        } else if (OUTMODE == 2) {
          int bb = m / N_, nn = m - bb * N_;
          int hh = n >> 5, dd = n & 31;
          ((short*)Cp)[((size_t)((bb*H_ + hh)*DH + dd))*N_ + nn] = f2bf_s(v);
        } else if (OUTMODE == 3) {
          if (n < 256) ((short*)Cp )[(size_t)m*256 + n]       = f2bf_s(v);
          else         ((short*)Cp2)[(size_t)m*256 + (n-256)] = f2bf_s(v);
        } else {
          if (n < 256) ((float*)Cp )[(size_t)m*256 + n]       = v;
          else         ((float*)Cp2)[(size_t)m*128 + (n-256)] = v;
        }
      }
    }
  }
}

// ---------------------------------------------------------------- MFMA flash attention
__global__ __launch_bounds__(64) void mfma_attn_kernel(
    const __hip_bfloat16* __restrict__ Q,
    const __hip_bfloat16* __restrict__ K,
    const __hip_bfloat16* __restrict__ Vt,
    float* __restrict__ O)
{
  const int NQT = 57;
  int wid = blockIdx.x;
  int qt = wid % NQT, bh = wid / NQT;
  int b = bh >> 3, h = bh & 7;
  int lane = threadIdx.x;
  int g = lane >> 4, r = lane & 15;
  int q0 = qt * 16;
  const float scale = 0.17677669529663687f;

  union U { bf16x8 v; short s[8]; unsigned long long u64[2]; };

  U qf;
  {
    int qrow = min(q0 + r, N_ - 1);
    const __hip_bfloat16* qp = Q + ((size_t)(b*N_ + qrow))*D_ + h*DH;
    qf.u64[0] = *(const unsigned long long*)(qp + 4*g);
    qf.u64[1] = *(const unsigned long long*)(qp + 16 + 4*g);
  }

  f32x4 oacc0 = {0.f,0.f,0.f,0.f};
  f32x4 oacc1 = {0.f,0.f,0.f,0.f};
  float m = -1e30f, l = 0.0f;
  const f32x4 zero = {0.f,0.f,0.f,0.f};

  const __hip_bfloat16* vbase0 = Vt + (size_t)(bh*DH + r) * N_;
  const __hip_bfloat16* vbase1 = Vt + (size_t)(bh*DH + 16 + r) * N_;

  for (int kt = 0; kt < N_; kt += 32) {
    U kf0, kf1;
    {
      int kr0 = min(kt + r, N_ - 1);
      int kr1 = min(kt + 16 + r, N_ - 1);
      const __hip_bfloat16* kp0 = K + ((size_t)(b*N_ + kr0))*D_ + h*DH;
      const __hip_bfloat16* kp1 = K + ((size_t)(b*N_ + kr1))*D_ + h*DH;
      kf0.u64[0] = *(const unsigned long long*)(kp0 + 4*g);
      kf0.u64[1] = *(const unsigned long long*)(kp0 + 16 + 4*g);
      kf1.u64[0] = *(const unsigned long long*)(kp1 + 4*g);
      kf1.u64[1] = *(const unsigned long long*)(kp1 + 16 + 4*g);
    }
    f32x4 s0 = __builtin_amdgcn_mfma_f32_16x16x32_bf16(kf0.v, qf.v, zero, 0, 0, 0);
    f32x4 s1 = __builtin_amdgcn_mfma_f32_16x16x32_bf16(kf1.v, qf.v, zero, 0, 0, 0);

    float sc[8];
    #pragma unroll
    for (int j = 0; j < 4; ++j) {
      sc[j]   = (kt + 4*g + j      < N_) ? s0[j] * scale : -1e30f;
      sc[4+j] = (kt + 16 + 4*g + j < N_) ? s1[j] * scale : -1e30f;
    }
    float mx = sc[0];
    #pragma unroll
    for (int j = 1; j < 8; ++j) mx = fmaxf(mx, sc[j]);
    mx = fmaxf(mx, __shfl_xor(mx, 16));
    mx = fmaxf(mx, __shfl_xor(mx, 32));

    float mnew = fmaxf(m, mx);
    float corr = __expf(m - mnew);
    float p[8], ps = 0.f;
    #pragma unroll
    for (int j = 0; j < 8; ++j) { p[j] = __expf(sc[j] - mnew); ps += p[j]; }
    ps += __shfl_xor(ps, 16);
    ps += __shfl_xor(ps, 32);
    l = l * corr + ps;
    m = mnew;
    #pragma unroll
    for (int j = 0; j < 4; ++j) { oacc0[j] *= corr; oacc1[j] *= corr; }

    U pf;
    #pragma unroll
    for (int j = 0; j < 8; ++j) pf.s[j] = f2bf_s(p[j]);

    U vf0, vf1;
    vf0.u64[0] = *(const unsigned long long*)(vbase0 + kt + 4*g);
    vf0.u64[1] = *(const unsigned long long*)(vbase0 + kt + 16 + 4*g);
    vf1.u64[0] = *(const unsigned long long*)(vbase1 + kt + 4*g);
    vf1.u64[1] = *(const unsigned long long*)(vbase1 + kt + 16 + 4*g);

    oacc0 = __builtin_amdgcn_mfma_f32_16x16x32_bf16(vf0.v, pf.v, oacc0, 0, 0, 0);
    oacc1 = __builtin_amdgcn_mfma_f32_16x16x32_bf16(vf1.v, pf.v, oacc1, 0, 0, 0);
  }

  if (q0 + r < N_) {
    float inv = 1.0f / l;
    float* op = O + ((size_t)(b*N_ + q0 + r))*D_ + h*DH;
    #pragma unroll
    for (int j = 0; j < 4; ++j) {
      op[4*g + j]      = oacc0[j] * inv;
      op[16 + 4*g + j] = oacc1[j] * inv;
    }
  }
}

// ---------------------------------------------------------------- add + LayerNorm
__global__ __launch_bounds__(256) void add_ln_kernel(
    const float* __restrict__ X, const float* __restrict__ Y,
    const float* __restrict__ g, const float* __restrict__ beta,
    float* __restrict__ out)
{
  int row = blockIdx.x, tid = threadIdx.x;
  float v = X[(size_t)row*D_ + tid] + Y[(size_t)row*D_ + tid];
  float s = v, s2 = v*v;
  #pragma unroll
  for (int off = 32; off; off >>= 1) {
    s  += __shfl_down(s,  off, 64);
    s2 += __shfl_down(s2, off, 64);
  }
  __shared__ float red[8];
  int wid = tid >> 6, lane = tid & 63;
  if (lane == 0) { red[wid] = s; red[wid+4] = s2; }
  __syncthreads();
  if (tid == 0) {
    float ts  = red[0]+red[1]+red[2]+red[3];
    float ts2 = red[4]+red[5]+red[6]+red[7];
    float mu  = ts * (1.0f/D_);
    float var = ts2 * (1.0f/D_) - mu*mu;
    red[0] = mu;
    red[1] = rsqrtf(fmaxf(var, 0.0f) + 1e-5f);
  }
  __syncthreads();
  float mu = red[0], rr = red[1];
  out[(size_t)row*D_ + tid] = (v - mu)*rr*g[tid] + beta[tid];
}

// ---------------------------------------------------------------- deformable sampling
__global__ __launch_bounds__(256) void sample_kernel(
    const __hip_bfloat16* __restrict__ V, const float* __restrict__ offp,
    const float* __restrict__ awl, const float* __restrict__ refp,
    float* __restrict__ out)
{
  int row = blockIdx.x;
  int b = row / N_;
  int tid = threadIdx.x;
  __shared__ float s_aw[128];
  __shared__ float s_loc[256];
  if (tid < 128) s_aw[tid] = awl[(size_t)row*128 + tid];
  {
    int rem = tid & 31;
    int l = rem >> 3, ax = rem & 1;
    const float norms[4] = {128.f, 64.f, 32.f, 16.f};
    float off = offp[(size_t)row*256 + tid];
    float rp  = refp[((size_t)row*4 + l)*2 + ax];
    s_loc[tid] = rp + off / norms[l];
  }
  __syncthreads();
  if (tid < 8) {
    float mx = -1e30f;
    for (int j = 0; j < 16; ++j) mx = fmaxf(mx, s_aw[tid*16+j]);
    float sum = 0.f;
    for (int j = 0; j < 16; ++j) sum += __expf(s_aw[tid*16+j] - mx);
    float inv = 1.0f / sum;
    for (int j = 0; j < 16; ++j) s_aw[tid*16+j] = __expf(s_aw[tid*16+j] - mx) * inv;
  }
  __syncthreads();
  int h = tid >> 5, d = tid & 31;
  const int dims[4]   = {128, 64, 32, 16};
  const int starts[4] = {0, 16384, 20480, 21504};
  const __hip_bfloat16* Vb = V + ((size_t)b*S_)*D_ + h*DH + d;
  float acc = 0.f;
  #pragma unroll
  for (int l = 0; l < 4; ++l) {
    int Wl = dims[l], st = starts[l];
    #pragma unroll
    for (int p = 0; p < 4; ++p) {
      float lx = s_loc[h*32 + l*8 + p*2 + 0];
      float ly = s_loc[h*32 + l*8 + p*2 + 1];
      float x = lx * Wl - 0.5f, y = ly * Wl - 0.5f;
      float x0f = floorf(x), y0f = floorf(y);
      float fx = x - x0f, fy = y - y0f;
      int x0 = (int)x0f, y0 = (int)y0f;
      float v = 0.f;
      #pragma unroll
      for (int ty = 0; ty < 2; ++ty) {
        int yi = y0 + ty;
        float wy = ty ? fy : (1.f - fy);
        if (yi < 0 || yi >= Wl) continue;
        #pragma unroll
        for (int txi = 0; txi < 2; ++txi) {
          int xi = x0 + txi;
          float wx = txi ? fx : (1.f - fx);
          if (xi < 0 || xi >= Wl) continue;
          v += wy * wx * __bfloat162float(Vb[(size_t)(st + yi*Wl + xi) * D_]);
        }
      }
      acc += s_aw[h*16 + l*4 + p] * v;
    }
  }
  out[(size_t)row*D_ + tid] = acc;
}

// ================================================================ launch
extern "C" void kernel_launch(void* const* d_in, const int* in_sizes, int n_in,
                              void* d_out, int out_size, void* d_ws, size_t ws_size,
                              hipStream_t stream)
{
  const float* tgt    = (const float*)d_in[0];
  const float* memory = (const float*)d_in[1];
  const float* qpos   = (const float*)d_in[2];
  const float* boxes  = (const float*)d_in[3];
  const float* refp   = (const float*)d_in[4];
  const float* wq = (const float*)d_in[5];   const float* bq = (const float*)d_in[6];
  const float* wk = (const float*)d_in[7];   const float* bk = (const float*)d_in[8];
  const float* wv = (const float*)d_in[9];   const float* bv = (const float*)d_in[10];
  const float* sa_wo = (const float*)d_in[11]; const float* sa_bo = (const float*)d_in[12];
  const float* n1g = (const float*)d_in[13]; const float* n1b = (const float*)d_in[14];
  const float* off_w = (const float*)d_in[15]; const float* off_b = (const float*)d_in[16];
  const float* aw_w  = (const float*)d_in[17]; const float* aw_b  = (const float*)d_in[18];
  const float* val_w = (const float*)d_in[19]; const float* val_b = (const float*)d_in[20];
  const float* co_w  = (const float*)d_in[21]; const float* co_b  = (const float*)d_in[22];
  const float* n2g = (const float*)d_in[23]; const float* n2b = (const float*)d_in[24];
  const float* ff1_w = (const float*)d_in[25]; const float* ff1_b = (const float*)d_in[26];
  const float* ff2_w = (const float*)d_in[27]; const float* ff2_b = (const float*)d_in[28];
  const float* n3g = (const float*)d_in[29]; const float* n3b = (const float*)d_in[30];

  char* ws = (char*)d_ws;
  size_t NE = (size_t)NROWS * D_;
  __hip_bfloat16* Vv = (__hip_bfloat16*)ws;     // value bf16 (89 MB)
  __hip_bfloat16* FFM = (__hip_bfloat16*)ws;    // ffn hidden bf16 overlays
  size_t p = (size_t)B_ * S_ * D_ * sizeof(__hip_bfloat16);
  float* A  = (float*)(ws + p); p += NE*4;      // rope out
  float* Qb = (float*)(ws + p); p += NE*4;      // q bf16 / off fp32
  float* Kb = (float*)(ws + p); p += NE*4;      // k bf16 / aw fp32 (first half); Wt in tail
  float* Vh = (float*)(ws + p); p += NE*4;      // Vt bf16 (attn V transposed)
  float* S1 = (float*)(ws + p); p += NE*4;      // attn out / sampled
  float* S2 = (float*)(ws + p); p += NE*4;      // proj out
  float* T1 = (float*)(ws + p); p += NE*4;      // tgt1 / tgt2
  short* Wt = (short*)((char*)Kb + NE*2);       // 3.08 MB in free tail of Kb
  float* out = (float*)d_out;
  (void)ws_size; (void)in_sizes; (void)n_in; (void)out_size;

  const short* qk_t  = Wt;                 // [512][256]
  const short* wv_t  = Wt + 131072;
  const short* sa_t  = Wt + 196608;
  const short* offaw_t = Wt + 262144;      // [384][256]
  const short* val_t = Wt + 360448;
  const short* co_t  = Wt + 425984;
  const short* ff1_t = Wt + 491520;
  const short* ff2_t = Wt + 1015808;

  wtrans_kernel<<<1504, 256, 0, stream>>>(wq, wk, wv, sa_wo, off_w, val_w,
                                          co_w, aw_w, ff1_w, ff2_w, Wt);

  // self-attention branch
  rope_kernel<<<NROWS, 128, 0, stream>>>(tgt, qpos, boxes, A);
  mgemm_kernel<32,256,false,false,false,3><<<dim3(225,2), 256, 0, stream>>>(
      A, nullptr, qk_t, bq, bk, Qb, Kb, NROWS, 512);
  mgemm_kernel<32,256,false,false,false,2><<<dim3(225,1), 256, 0, stream>>>(
      tgt, nullptr, wv_t, bv, nullptr, Vh, nullptr, NROWS, 256);
  mfma_attn_kernel<<<57 * B_ * H_, 64, 0, stream>>>(
      (const __hip_bfloat16*)Qb, (const __hip_bfloat16*)Kb,
      (const __hip_bfloat16*)Vh, S1);
  mgemm_kernel<32,256,false,false,false,0><<<dim3(225,1), 256, 0, stream>>>(
      S1, nullptr, sa_t, sa_bo, nullptr, S2, nullptr, NROWS, 256);
  add_ln_kernel<<<NROWS, 256, 0, stream>>>(tgt, S2, n1g, n1b, T1);

  // cross-attention branch
  mgemm_kernel<64,256,false,false,false,1><<<dim3(2720,1), 256, 0, stream>>>(
      memory, nullptr, val_t, val_b, nullptr, Vv, nullptr, B_*S_, 256);
  mgemm_kernel<32,256,false,true,false,4><<<dim3(225,2), 256, 0, stream>>>(
      T1, qpos, offaw_t, off_b, aw_b, Qb, Kb, NROWS, 384);
  sample_kernel<<<NROWS, 256, 0, stream>>>(Vv, Qb, Kb, refp, S1);
  mgemm_kernel<32,256,false,false,false,0><<<dim3(225,1), 256, 0, stream>>>(
      S1, nullptr, co_t, co_b, nullptr, S2, nullptr, NROWS, 256);
  add_ln_kernel<<<NROWS, 256, 0, stream>>>(T1, S2, n2g, n2b, T1);

  // ffn
  mgemm_kernel<32,256,false,false,true,1><<<dim3(225,8), 256, 0, stream>>>(
      T1, nullptr, ff1_t, ff1_b, nullptr, FFM, nullptr, NROWS, FF_);
  mgemm_kernel<32,2048,true,false,false,0><<<dim3(225,1), 256, 0, stream>>>(
      FFM, nullptr, ff2_t, ff2_b, nullptr, S2, nullptr, NROWS, 256);
  add_ln_kernel<<<NROWS, 256, 0, stream>>>(T1, S2, n3g, n3b, out);
}